// Round 11
// baseline (1336.087 us; speedup 1.0000x reference)
//
// Round 11: B never touches LDS — per-wave register dequant from packed q (1 dword = 1 MFMA
// k-octet via permuted pack), software-pipelined one K-tile ahead. LDS holds only A (dbuf
// 64KB, gload_lds + XOR swizzle, proven). One barrier/K-tile guarding A-DMA only.
#include <hip/hip_runtime.h>
#include <stdint.h>

#define TOKENS 8192
#define KDIM   4096
#define NDIM   11008
#define BM 256
#define BN 256
#define BK 64
#define KTILES (KDIM / BK)          // 64
#define QWPR 512                    // packed dwords per q row
#define PQ_BYTES (45088768u/8u*4u)  // 22544384
#define XH_BYTES (33554432ull*2ull) // 67108864
#define WS_PACKED ((size_t)PQ_BYTES + XH_BYTES)

typedef _Float16 f16x8 __attribute__((ext_vector_type(8)));
typedef _Float16 f16x2 __attribute__((ext_vector_type(2)));
typedef float    f32x4 __attribute__((ext_vector_type(4)));

typedef const __attribute__((address_space(1))) unsigned int* gptr_t;
typedef __attribute__((address_space(3))) unsigned int* lptr_t;

// ---- pass 1a: pack 8 nibbles -> 1 dword, PERMUTED [k0,k2,k4,k6,k1,k3,k5,k7]:
// ((d>>4p)&0x000F000F)|0x64006400 = fp16 pair (1024+k_{2p}, 1024+k_{2p+1}).
__global__ __launch_bounds__(256) void pack_q(const int* __restrict__ q,
                                              unsigned int* __restrict__ pq) {
    const unsigned int idx = blockIdx.x * 256 + threadIdx.x;
    const int4* p = (const int4*)(q + (size_t)idx * 8);
    const int4 a = p[0], b = p[1];
    unsigned int w = (unsigned int)(a.x & 15)
                   | ((unsigned int)(a.z & 15) << 4)
                   | ((unsigned int)(b.x & 15) << 8)
                   | ((unsigned int)(b.z & 15) << 12)
                   | ((unsigned int)(a.y & 15) << 16)
                   | ((unsigned int)(a.w & 15) << 20)
                   | ((unsigned int)(b.y & 15) << 24)
                   | ((unsigned int)(b.w & 15) << 28);
    pq[idx] = w;
}

// ---- pass 1b: x fp32 -> fp16 (exact) ----
__global__ __launch_bounds__(256) void cvt_x(const float* __restrict__ x,
                                             _Float16* __restrict__ xh) {
    const size_t idx = (size_t)(blockIdx.x * 256 + threadIdx.x) * 8;
    const float4* p = (const float4*)(x + idx);
    const float4 a = p[0], b = p[1];
    f16x8 o;
    o[0] = (_Float16)a.x; o[1] = (_Float16)a.y; o[2] = (_Float16)a.z; o[3] = (_Float16)a.w;
    o[4] = (_Float16)b.x; o[5] = (_Float16)b.y; o[6] = (_Float16)b.z; o[7] = (_Float16)b.w;
    *(f16x8*)(xh + idx) = o;
}

// ---- pass 2: 256x256x64, 8 waves; A in dbuf LDS, B dequanted in registers ----
__global__ __launch_bounds__(512, 2)
void wq_gemm_rb(const _Float16* __restrict__ Xh, const unsigned int* __restrict__ Pq,
                const float* __restrict__ Sc, const float* __restrict__ Zp,
                const float* __restrict__ Bi, float* __restrict__ Out)
{
    __shared__ __align__(16) _Float16 As[2][BM * BK];   // 2 x 32 KB

    const int t    = threadIdx.x;
    const int lane = t & 63;
    const int wid  = t >> 6;        // 0..7
    const int wmr  = wid >> 2;      // 0..1 : rows wmr*128..+128
    const int wnc  = wid & 3;       // 0..3 : cols wnc*64..+64

    // XCD-bijective, n-fastest (1376 = 8*172)
    const unsigned int bid = blockIdx.x;
    const unsigned int wg  = (bid & 7u) * 172u + (bid >> 3);
    const int m0 = (int)(wg / 43u) * BM;
    const int n0 = (int)(wg % 43u) * BN;

    // A staging (identical to R10, measured conflict-free): 4 issues/wave,
    // linear LDS dest, pre-XOR'd global source: phys blk = logical ^ (row&7).
    const int alr = lane >> 3;
    const int alb = lane & 7;
    const _Float16* aSrc = Xh + (size_t)(m0 + wid * 8 + alr) * KDIM + ((alb ^ alr) << 3);

    // fragment read map
    const int fr = lane & 15;
    const int fq = lane >> 4;       // 0..3
    const int fx = fr & 7;

    // B per-lane sources: column n_j = n0 + wnc*64 + j*16 + fr
    const unsigned int* qrow[4];
    const float* scol[4];
    const float* zcol[4];
#pragma unroll
    for (int j = 0; j < 4; ++j) {
        const int nj = n0 + wnc * 64 + j * 16 + fr;
        qrow[j] = Pq + (size_t)nj * QWPR + fq;   // + kt*8 + kh*4 per load
        scol[j] = Sc + nj;                       // + g*NDIM
        zcol[j] = Zp + nj;
    }

    f32x4 acc[8][4];
#pragma unroll
    for (int i = 0; i < 8; ++i)
#pragma unroll
        for (int j = 0; j < 4; ++j)
            acc[i][j] = f32x4{0.f, 0.f, 0.f, 0.f};

    const f16x2 k1024 = {(_Float16)1024.0f, (_Float16)1024.0f};

#define A_STAGE(buf, ktv) do {                                                        \
    _Pragma("unroll")                                                                 \
    for (int i_ = 0; i_ < 4; ++i_)                                                    \
        __builtin_amdgcn_global_load_lds(                                             \
            (gptr_t)(const void*)(aSrc + (size_t)i_ * 64 * KDIM + (ktv) * BK),        \
            (lptr_t)(void*)(&As[buf][i_ * 4096 + wid * 512]), 16, 0, 0);              \
} while (0)

#define DEQ_FRAG(dst, dw, s2v, z2v) do {                                              \
    unsigned int o_[4];                                                               \
    _Pragma("unroll")                                                                 \
    for (int p_ = 0; p_ < 4; ++p_) {                                                  \
        unsigned int u_ = (((dw) >> (4 * p_)) & 0x000F000Fu) | 0x64006400u;           \
        f16x2 h_ = __builtin_bit_cast(f16x2, u_);                                     \
        f16x2 q_ = h_ - k1024;                                                        \
        f16x2 w_ = q_ * (s2v) + (z2v);                                                \
        o_[p_] = __builtin_bit_cast(unsigned int, w_);                                \
    }                                                                                 \
    (dst) = __builtin_bit_cast(f16x8, uint4{o_[0], o_[1], o_[2], o_[3]});             \
} while (0)

// one K-tile: stage next A, load next raw q (+optionally next s/z), dequant current
// B in regs, 4 MFMA phases, barrier (drains A-DMA that had the whole iter to land).
#define ITER(CUR, RAWc, RAWn, S2c, Z2c, S2n, Z2n, KT, LOADSZ, GN) do {                \
    const int ktn_ = ((KT) + 1 < KTILES) ? (KT) + 1 : (KT);                           \
    A_STAGE((CUR) ^ 1, ktn_);                                                         \
    _Pragma("unroll")                                                                 \
    for (int j_ = 0; j_ < 4; ++j_) {                                                  \
        RAWn[j_][0] = qrow[j_][(size_t)ktn_ * 8];                                     \
        RAWn[j_][1] = qrow[j_][(size_t)ktn_ * 8 + 4];                                 \
    }                                                                                 \
    if (LOADSZ) {                                                                     \
        const int gn_ = (GN) < 32 ? (GN) : 31;                                        \
        _Pragma("unroll")                                                             \
        for (int j_ = 0; j_ < 4; ++j_) {                                              \
            const float s_ = scol[j_][(size_t)gn_ * NDIM];                            \
            const float z_ = zcol[j_][(size_t)gn_ * NDIM];                            \
            S2n[j_] = f16x2{(_Float16)s_, (_Float16)s_};                              \
            Z2n[j_] = f16x2{(_Float16)z_, (_Float16)z_};                              \
        }                                                                             \
    }                                                                                 \
    f16x8 bb_[4][2];                                                                  \
    _Pragma("unroll")                                                                 \
    for (int j_ = 0; j_ < 4; ++j_) {                                                  \
        DEQ_FRAG(bb_[j_][0], RAWc[j_][0], S2c[j_], Z2c[j_]);                          \
        DEQ_FRAG(bb_[j_][1], RAWc[j_][1], S2c[j_], Z2c[j_]);                          \
    }                                                                                 \
    _Pragma("unroll")                                                                 \
    for (int p_ = 0; p_ < 4; ++p_) {                                                  \
        f16x8 a_[2][2];                                                               \
        _Pragma("unroll")                                                             \
        for (int ii_ = 0; ii_ < 2; ++ii_)                                             \
            _Pragma("unroll")                                                         \
            for (int kh_ = 0; kh_ < 2; ++kh_)                                         \
                a_[ii_][kh_] = *(const f16x8*)&As[CUR][                               \
                    (wmr * 128 + (p_ * 2 + ii_) * 16 + fr) * 64 +                     \
                    (((kh_ << 2) | fq) ^ fx) * 8];                                    \
        __builtin_amdgcn_s_setprio(1);                                                \
        _Pragma("unroll")                                                             \
        for (int ii_ = 0; ii_ < 2; ++ii_)                                             \
            _Pragma("unroll")                                                         \
            for (int j_ = 0; j_ < 4; ++j_) {                                          \
                acc[p_ * 2 + ii_][j_] = __builtin_amdgcn_mfma_f32_16x16x32_f16(       \
                    a_[ii_][0], bb_[j_][0], acc[p_ * 2 + ii_][j_], 0, 0, 0);          \
                acc[p_ * 2 + ii_][j_] = __builtin_amdgcn_mfma_f32_16x16x32_f16(       \
                    a_[ii_][1], bb_[j_][1], acc[p_ * 2 + ii_][j_], 0, 0, 0);          \
            }                                                                         \
        __builtin_amdgcn_s_setprio(0);                                                \
    }                                                                                 \
    __syncthreads();                                                                  \
} while (0)

    unsigned int rawA[4][2], rawB[4][2];
    f16x2 s2A[4], z2A[4], s2B[4], z2B[4];

    // prologue: A tile 0 DMA; raw q for kt=0; s/z for group 0
    A_STAGE(0, 0);
#pragma unroll
    for (int j = 0; j < 4; ++j) {
        rawA[j][0] = qrow[j][0];
        rawA[j][1] = qrow[j][4];
        const float s_ = scol[j][0];
        const float z_ = zcol[j][0];
        s2A[j] = f16x2{(_Float16)s_, (_Float16)s_};
        z2A[j] = f16x2{(_Float16)z_, (_Float16)z_};
    }
    __syncthreads();

    // 64 K-tiles; group g = kt>>1 flips every pair; sz double-buffered A/B
    for (int pp = 0; pp < 32; pp += 2) {
        ITER(0, rawA, rawB, s2A, z2A, s2B, z2B, pp * 2,     true,  pp + 1);
        ITER(1, rawB, rawA, s2A, z2A, s2B, z2B, pp * 2 + 1, false, 0);
        ITER(0, rawA, rawB, s2B, z2B, s2A, z2A, pp * 2 + 2, true,  pp + 2);
        ITER(1, rawB, rawA, s2B, z2B, s2A, z2A, pp * 2 + 3, false, 0);
    }
#undef ITER
#undef DEQ_FRAG
#undef A_STAGE

    // epilogue: C/D map col=lane&15, row=(lane>>4)*4+reg; out = f32(f16(acc)+f16(bias))
#pragma unroll
    for (int j = 0; j < 4; ++j) {
        const int n = n0 + wnc * 64 + j * 16 + fr;
        const _Float16 bv = (_Float16)Bi[n];
#pragma unroll
        for (int im = 0; im < 8; ++im) {
            const int mbase = m0 + wmr * 128 + im * 16 + fq * 4;
#pragma unroll
            for (int r = 0; r < 4; ++r) {
                const _Float16 h = (_Float16)acc[im][j][r] + bv;
                __builtin_nontemporal_store((float)h, &Out[(size_t)(mbase + r) * NDIM + n]);
            }
        }
    }
}

// ---------------- fallback: round-5 direct kernel (no workspace) ----------------
__global__ __launch_bounds__(256, 2)
void wq_gemm_direct(const float* __restrict__ X,  const int* __restrict__ Qw,
                    const float* __restrict__ Sc, const float* __restrict__ Zp,
                    const float* __restrict__ Bi, float* __restrict__ Out)
{
    __shared__ __align__(16) _Float16 As[128 * 32];
    __shared__ __align__(16) _Float16 Bs[128 * 32];
    const int t = threadIdx.x, lane = t & 63, wid = t >> 6;
    const int wr = wid >> 1, wc = wid & 1;
    const int n0 = blockIdx.x * 128, m0 = blockIdx.y * 128;
    const int srow = t >> 1, shalf = (t & 1) << 4;
    const float* xsrc = X + (size_t)(m0 + srow) * KDIM + shalf;
    const int*   qsrc = Qw + (size_t)(n0 + srow) * KDIM + shalf;
    const float* scp = Sc + n0 + srow;
    const float* zpp = Zp + n0 + srow;
    _Float16* adst = As + srow * 32 + shalf;
    _Float16* bdst = Bs + srow * 32 + shalf;
    const int fr = lane & 15, fq = lane >> 4;
    const _Float16* ard = As + (wr * 64 + fr) * 32 + fq * 8;
    const _Float16* brd = Bs + (wc * 64 + fr) * 32 + fq * 8;
    f32x4 acc[4][4];
#pragma unroll
    for (int i = 0; i < 4; ++i)
#pragma unroll
        for (int j = 0; j < 4; ++j) acc[i][j] = f32x4{0.f, 0.f, 0.f, 0.f};
    for (int kt = 0; kt < KDIM / 32; ++kt) {
        const int k0 = kt * 32;
        const float4* xp = (const float4*)(xsrc + k0);
        const float4 x0 = xp[0], x1 = xp[1], x2 = xp[2], x3 = xp[3];
        const float xv[16] = {x0.x, x0.y, x0.z, x0.w, x1.x, x1.y, x1.z, x1.w,
                              x2.x, x2.y, x2.z, x2.w, x3.x, x3.y, x3.z, x3.w};
        f16x8 a0, a1;
#pragma unroll
        for (int j = 0; j < 8; ++j) { a0[j] = (_Float16)xv[j]; a1[j] = (_Float16)xv[j + 8]; }
        const int g = k0 >> 7;
        const float sf = scp[(size_t)g * NDIM];
        const float zf = zpp[(size_t)g * NDIM];
        const int4* qp = (const int4*)(qsrc + k0);
        const int4 q0 = qp[0], q1 = qp[1], q2 = qp[2], q3 = qp[3];
        const int qv[16] = {q0.x, q0.y, q0.z, q0.w, q1.x, q1.y, q1.z, q1.w,
                            q2.x, q2.y, q2.z, q2.w, q3.x, q3.y, q3.z, q3.w};
        f16x8 w0, w1;
#pragma unroll
        for (int j = 0; j < 8; ++j) {
            w0[j] = (_Float16)((float)qv[j]     * sf + zf);
            w1[j] = (_Float16)((float)qv[j + 8] * sf + zf);
        }
        *(f16x8*)adst = a0; *(f16x8*)(adst + 8) = a1;
        *(f16x8*)bdst = w0; *(f16x8*)(bdst + 8) = w1;
        __syncthreads();
        f16x8 a[4], b[4];
#pragma unroll
        for (int i = 0; i < 4; ++i) a[i] = *(const f16x8*)(ard + i * 16 * 32);
#pragma unroll
        for (int j = 0; j < 4; ++j) b[j] = *(const f16x8*)(brd + j * 16 * 32);
#pragma unroll
        for (int i = 0; i < 4; ++i)
#pragma unroll
            for (int j = 0; j < 4; ++j)
                acc[i][j] = __builtin_amdgcn_mfma_f32_16x16x32_f16(a[i], b[j], acc[i][j], 0, 0, 0);
        __syncthreads();
    }
#pragma unroll
    for (int j = 0; j < 4; ++j) {
        const int n = n0 + wc * 64 + j * 16 + fr;
        const _Float16 bv = (_Float16)Bi[n];
#pragma unroll
        for (int i = 0; i < 4; ++i) {
            const int mbase = m0 + wr * 64 + i * 16 + fq * 4;
#pragma unroll
            for (int r = 0; r < 4; ++r) {
                const _Float16 h = (_Float16)acc[i][j][r] + bv;
                Out[(size_t)(mbase + r) * NDIM + n] = (float)h;
            }
        }
    }
}

extern "C" void kernel_launch(void* const* d_in, const int* in_sizes, int n_in,
                              void* d_out, int out_size, void* d_ws, size_t ws_size,
                              hipStream_t stream) {
    const float* x  = nullptr;
    const int*   q  = nullptr;
    const float* sc = nullptr;
    const float* zp = nullptr;
    const float* bi = nullptr;
    for (int i = 0; i < n_in; ++i) {
        switch (in_sizes[i]) {
            case 33554432: x = (const float*)d_in[i]; break;
            case 45088768: q = (const int*)d_in[i]; break;
            case 352256:   if (!sc) sc = (const float*)d_in[i];
                           else     zp = (const float*)d_in[i];
                           break;
            case 11008:    bi = (const float*)d_in[i]; break;
            default: break;
        }
    }
    if (!x || !q || !sc || !zp || !bi) {
        x  = (const float*)d_in[0];
        q  = (const int*)d_in[1];
        sc = (const float*)d_in[2];
        zp = (const float*)d_in[3];
        bi = (const float*)d_in[4];
    }
    float* out = (float*)d_out;

    if (ws_size >= WS_PACKED) {
        unsigned int* pq = (unsigned int*)d_ws;
        _Float16*     xh = (_Float16*)((char*)d_ws + PQ_BYTES);
        pack_q<<<5636096 / 256, 256, 0, stream>>>(q, pq);
        cvt_x<<<33554432 / 8 / 256, 256, 0, stream>>>(x, xh);
        wq_gemm_rb<<<(TOKENS / BM) * (NDIM / BN), 512, 0, stream>>>(xh, pq, sc, zp, bi, out);
    } else {
        dim3 grid(NDIM / 128, TOKENS / 128);
        wq_gemm_direct<<<grid, dim3(256), 0, stream>>>(x, q, sc, zp, bi, out);
    }
}

// Round 12
// 928.927 us; speedup vs baseline: 1.4383x; 1.4383x over previous
//
// Round 12: R10 base (882us, coalesced staging) + q carried TWO tiles in registers so
// DEQ_STORE has no vmcnt wait and sits BEFORE the MFMA phases (kills the serial tail).
// 256x256x64, 8 waves, dbuf LDS 128KB, gload_lds+XOR swizzle A, pk-magic dequant B,
// n-fastest XCD order, setprio around MFMA, NT stores.
#include <hip/hip_runtime.h>
#include <stdint.h>

#define TOKENS 8192
#define KDIM   4096
#define NDIM   11008
#define BM 256
#define BN 256
#define BK 64
#define KTILES (KDIM / BK)          // 64
#define QWPR 512                    // packed dwords per q row
#define PQ_BYTES (45088768u/8u*4u)  // 22544384
#define XH_BYTES (33554432ull*2ull) // 67108864
#define WS_PACKED ((size_t)PQ_BYTES + XH_BYTES)

typedef _Float16 f16x8 __attribute__((ext_vector_type(8)));
typedef _Float16 f16x2 __attribute__((ext_vector_type(2)));
typedef float    f32x4 __attribute__((ext_vector_type(4)));

typedef const __attribute__((address_space(1))) unsigned int* gptr_t;
typedef __attribute__((address_space(3))) unsigned int* lptr_t;

// ---- pass 1a: pack 8 nibbles -> 1 dword, PERMUTED [k0,k2,k4,k6,k1,k3,k5,k7]:
// ((d>>4p)&0x000F000F)|0x64006400 = fp16 pair (1024+k_{2p}, 1024+k_{2p+1}).
__global__ __launch_bounds__(256) void pack_q(const int* __restrict__ q,
                                              unsigned int* __restrict__ pq) {
    const unsigned int idx = blockIdx.x * 256 + threadIdx.x;
    const int4* p = (const int4*)(q + (size_t)idx * 8);
    const int4 a = p[0], b = p[1];
    unsigned int w = (unsigned int)(a.x & 15)
                   | ((unsigned int)(a.z & 15) << 4)
                   | ((unsigned int)(b.x & 15) << 8)
                   | ((unsigned int)(b.z & 15) << 12)
                   | ((unsigned int)(a.y & 15) << 16)
                   | ((unsigned int)(a.w & 15) << 20)
                   | ((unsigned int)(b.y & 15) << 24)
                   | ((unsigned int)(b.w & 15) << 28);
    pq[idx] = w;
}

// ---- pass 1b: x fp32 -> fp16 (exact) ----
__global__ __launch_bounds__(256) void cvt_x(const float* __restrict__ x,
                                             _Float16* __restrict__ xh) {
    const size_t idx = (size_t)(blockIdx.x * 256 + threadIdx.x) * 8;
    const float4* p = (const float4*)(x + idx);
    const float4 a = p[0], b = p[1];
    f16x8 o;
    o[0] = (_Float16)a.x; o[1] = (_Float16)a.y; o[2] = (_Float16)a.z; o[3] = (_Float16)a.w;
    o[4] = (_Float16)b.x; o[5] = (_Float16)b.y; o[6] = (_Float16)b.z; o[7] = (_Float16)b.w;
    *(f16x8*)(xh + idx) = o;
}

// ---- pass 2: 256^2 8-wave fused-dequant GEMM, pipelined q (no mid-tile vmcnt wait) ----
__global__ __launch_bounds__(512, 2)
void wq_gemm_pl(const _Float16* __restrict__ Xh, const unsigned int* __restrict__ Pq,
                const float* __restrict__ Sc, const float* __restrict__ Zp,
                const float* __restrict__ Bi, float* __restrict__ Out)
{
    __shared__ __align__(16) _Float16 As[2][BM * BK];   // 2 x 32 KB
    __shared__ __align__(16) _Float16 Bs[2][BN * BK];   // 2 x 32 KB

    const int t    = threadIdx.x;
    const int lane = t & 63;
    const int wid  = t >> 6;        // 0..7
    const int wmr  = wid >> 2;      // 0..1 : rows wmr*128..+128
    const int wnc  = wid & 3;       // 0..3 : cols wnc*64..+64

    // XCD-bijective, n-fastest (1376 = 8*172)
    const unsigned int bid = blockIdx.x;
    const unsigned int wg  = (bid & 7u) * 172u + (bid >> 3);
    const int m0 = (int)(wg / 43u) * BM;
    const int n0 = (int)(wg % 43u) * BN;

    // A staging (proven conflict-free): 4 gload_lds issues/wave, linear LDS dest,
    // pre-XOR'd global source: phys blk = logical ^ (row&7).
    const int alr = lane >> 3;
    const int alb = lane & 7;
    const _Float16* aSrc = Xh + (size_t)(m0 + wid * 8 + alr) * KDIM + ((alb ^ alr) << 3);

    // B staging: row br = t>>1 (0..255), half bh = t&1 (4 packed dwords = 32 nibbles)
    const int br = t >> 1;
    const int bh = t & 1;
    const unsigned int* qsrc = Pq + (size_t)(n0 + br) * QWPR + bh * 4;
    const float* scp = Sc + n0 + br;
    const float* zpp = Zp + n0 + br;
    const int brx = br & 7;

    // fragment read map
    const int fr = lane & 15;
    const int fq = lane >> 4;       // 0..3
    const int fx = fr & 7;

    f32x4 acc[8][4];
#pragma unroll
    for (int i = 0; i < 8; ++i)
#pragma unroll
        for (int j = 0; j < 4; ++j)
            acc[i][j] = f32x4{0.f, 0.f, 0.f, 0.f};

    const f16x2 k1024 = {(_Float16)1024.0f, (_Float16)1024.0f};

#define A_STAGE(buf, ktv) do {                                                        \
    _Pragma("unroll")                                                                 \
    for (int i_ = 0; i_ < 4; ++i_)                                                    \
        __builtin_amdgcn_global_load_lds(                                             \
            (gptr_t)(const void*)(aSrc + (size_t)i_ * 64 * KDIM + (ktv) * BK),        \
            (lptr_t)(void*)(&As[buf][i_ * 4096 + wid * 512]), 16, 0, 0);              \
} while (0)

#define DEQ_STORE(buf, qvv, sfv, zfv) do {                                            \
    const f16x2 s2_ = {(_Float16)(sfv), (_Float16)(sfv)};                             \
    const f16x2 z2_ = {(_Float16)(zfv), (_Float16)(zfv)};                             \
    _Pragma("unroll")                                                                 \
    for (int d_ = 0; d_ < 4; ++d_) {                                                  \
        const unsigned int dw_ = ((const unsigned int*)&(qvv))[d_];                   \
        unsigned int o_[4];                                                           \
        _Pragma("unroll")                                                             \
        for (int p_ = 0; p_ < 4; ++p_) {                                              \
            unsigned int u_ = ((dw_ >> (4 * p_)) & 0x000F000Fu) | 0x64006400u;        \
            f16x2 h_ = __builtin_bit_cast(f16x2, u_);                                 \
            f16x2 q_ = h_ - k1024;                                                    \
            f16x2 w_ = q_ * s2_ + z2_;                                                \
            o_[p_] = __builtin_bit_cast(unsigned int, w_);                            \
        }                                                                             \
        const int kb_ = (bh * 4 + d_) ^ brx;                                          \
        *(uint4*)&Bs[buf][br * 64 + kb_ * 8] = uint4{o_[0], o_[1], o_[2], o_[3]};     \
    }                                                                                 \
} while (0)

    // ---- prologue ----
    A_STAGE(0, 0);
    uint4 qcur = *(const uint4*)(qsrc);            // q for tile 0
    const float sf0 = scp[0];
    const float zf0 = zpp[0];
    __syncthreads();                               // qcur + tile-0 A-DMA landed
    DEQ_STORE(0, qcur, sf0, zf0);
    uint4 qnext = *(const uint4*)(qsrc + 8);       // q for tile 1 (group 0)
    float sfn = sf0, zfn = zf0;
    __syncthreads();                               // B tile-0 visible; qnext landed

    // ---- main loop: per tile, NO mid-tile vmcnt wait (qnext is register-resident) ----
    int cur = 0;
    for (int kt = 0; kt < KTILES; ++kt) {
        if (kt + 1 < KTILES) A_STAGE(cur ^ 1, kt + 1);

        // future q/sz (for tile kt+2); drained by this tile's end barrier
        const int ktf = (kt + 2 < KTILES) ? kt + 2 : KTILES - 1;
        const uint4 qfut = *(const uint4*)(qsrc + (size_t)ktf * 8);
        const int gf = ktf >> 1;
        const float sff = scp[(size_t)gf * NDIM];
        const float zff = zpp[(size_t)gf * NDIM];

        // write B for tile kt+1 into buf^1 — data already in regs, no wait;
        // compiler interleaves these VALU+ds_writes with the MFMA phases below.
        if (kt + 1 < KTILES) DEQ_STORE(cur ^ 1, qnext, sfn, zfn);

        // compute tile kt
        f16x8 bc[4][2];
#pragma unroll
        for (int j = 0; j < 4; ++j)
#pragma unroll
            for (int kh = 0; kh < 2; ++kh)
                bc[j][kh] = *(const f16x8*)&Bs[cur][(wnc * 64 + j * 16 + fr) * 64 +
                                                    (((kh << 2) | fq) ^ fx) * 8];
#pragma unroll
        for (int p = 0; p < 4; ++p) {
            f16x8 a[2][2];
#pragma unroll
            for (int ii = 0; ii < 2; ++ii)
#pragma unroll
                for (int kh = 0; kh < 2; ++kh)
                    a[ii][kh] = *(const f16x8*)&As[cur][(wmr * 128 + (p * 2 + ii) * 16 + fr) * 64 +
                                                        (((kh << 2) | fq) ^ fx) * 8];
            __builtin_amdgcn_s_setprio(1);
#pragma unroll
            for (int ii = 0; ii < 2; ++ii)
#pragma unroll
                for (int j = 0; j < 4; ++j) {
                    acc[p * 2 + ii][j] = __builtin_amdgcn_mfma_f32_16x16x32_f16(
                        a[ii][0], bc[j][0], acc[p * 2 + ii][j], 0, 0, 0);
                    acc[p * 2 + ii][j] = __builtin_amdgcn_mfma_f32_16x16x32_f16(
                        a[ii][1], bc[j][1], acc[p * 2 + ii][j], 0, 0, 0);
                }
            __builtin_amdgcn_s_setprio(0);
        }

        __syncthreads();   // drains A-DMA(kt+1) + qfut; all reads of cur done
        qnext = qfut; sfn = sff; zfn = zff;
        cur ^= 1;
    }
#undef A_STAGE
#undef DEQ_STORE

    // epilogue: C/D map col=lane&15, row=(lane>>4)*4+reg; out = f32(f16(acc)+f16(bias))
#pragma unroll
    for (int j = 0; j < 4; ++j) {
        const int n = n0 + wnc * 64 + j * 16 + fr;
        const _Float16 bv = (_Float16)Bi[n];
#pragma unroll
        for (int im = 0; im < 8; ++im) {
            const int mbase = m0 + wmr * 128 + im * 16 + fq * 4;
#pragma unroll
            for (int r = 0; r < 4; ++r) {
                const _Float16 h = (_Float16)acc[im][j][r] + bv;
                __builtin_nontemporal_store((float)h, &Out[(size_t)(mbase + r) * NDIM + n]);
            }
        }
    }
}

// ---------------- fallback: round-5 direct kernel (no workspace) ----------------
__global__ __launch_bounds__(256, 2)
void wq_gemm_direct(const float* __restrict__ X,  const int* __restrict__ Qw,
                    const float* __restrict__ Sc, const float* __restrict__ Zp,
                    const float* __restrict__ Bi, float* __restrict__ Out)
{
    __shared__ __align__(16) _Float16 As[128 * 32];
    __shared__ __align__(16) _Float16 Bs[128 * 32];
    const int t = threadIdx.x, lane = t & 63, wid = t >> 6;
    const int wr = wid >> 1, wc = wid & 1;
    const int n0 = blockIdx.x * 128, m0 = blockIdx.y * 128;
    const int srow = t >> 1, shalf = (t & 1) << 4;
    const float* xsrc = X + (size_t)(m0 + srow) * KDIM + shalf;
    const int*   qsrc = Qw + (size_t)(n0 + srow) * KDIM + shalf;
    const float* scp = Sc + n0 + srow;
    const float* zpp = Zp + n0 + srow;
    _Float16* adst = As + srow * 32 + shalf;
    _Float16* bdst = Bs + srow * 32 + shalf;
    const int fr = lane & 15, fq = lane >> 4;
    const _Float16* ard = As + (wr * 64 + fr) * 32 + fq * 8;
    const _Float16* brd = Bs + (wc * 64 + fr) * 32 + fq * 8;
    f32x4 acc[4][4];
#pragma unroll
    for (int i = 0; i < 4; ++i)
#pragma unroll
        for (int j = 0; j < 4; ++j) acc[i][j] = f32x4{0.f, 0.f, 0.f, 0.f};
    for (int kt = 0; kt < KDIM / 32; ++kt) {
        const int k0 = kt * 32;
        const float4* xp = (const float4*)(xsrc + k0);
        const float4 x0 = xp[0], x1 = xp[1], x2 = xp[2], x3 = xp[3];
        const float xv[16] = {x0.x, x0.y, x0.z, x0.w, x1.x, x1.y, x1.z, x1.w,
                              x2.x, x2.y, x2.z, x2.w, x3.x, x3.y, x3.z, x3.w};
        f16x8 a0, a1;
#pragma unroll
        for (int j = 0; j < 8; ++j) { a0[j] = (_Float16)xv[j]; a1[j] = (_Float16)xv[j + 8]; }
        const int g = k0 >> 7;
        const float sf = scp[(size_t)g * NDIM];
        const float zf = zpp[(size_t)g * NDIM];
        const int4* qp = (const int4*)(qsrc + k0);
        const int4 q0 = qp[0], q1 = qp[1], q2 = qp[2], q3 = qp[3];
        const int qv[16] = {q0.x, q0.y, q0.z, q0.w, q1.x, q1.y, q1.z, q1.w,
                            q2.x, q2.y, q2.z, q2.w, q3.x, q3.y, q3.z, q3.w};
        f16x8 w0, w1;
#pragma unroll
        for (int j = 0; j < 8; ++j) {
            w0[j] = (_Float16)((float)qv[j]     * sf + zf);
            w1[j] = (_Float16)((float)qv[j + 8] * sf + zf);
        }
        *(f16x8*)adst = a0; *(f16x8*)(adst + 8) = a1;
        *(f16x8*)bdst = w0; *(f16x8*)(bdst + 8) = w1;
        __syncthreads();
        f16x8 a[4], b[4];
#pragma unroll
        for (int i = 0; i < 4; ++i) a[i] = *(const f16x8*)(ard + i * 16 * 32);
#pragma unroll
        for (int j = 0; j < 4; ++j) b[j] = *(const f16x8*)(brd + j * 16 * 32);
#pragma unroll
        for (int i = 0; i < 4; ++i)
#pragma unroll
            for (int j = 0; j < 4; ++j)
                acc[i][j] = __builtin_amdgcn_mfma_f32_16x16x32_f16(a[i], b[j], acc[i][j], 0, 0, 0);
        __syncthreads();
    }
#pragma unroll
    for (int j = 0; j < 4; ++j) {
        const int n = n0 + wc * 64 + j * 16 + fr;
        const _Float16 bv = (_Float16)Bi[n];
#pragma unroll
        for (int i = 0; i < 4; ++i) {
            const int mbase = m0 + wr * 64 + i * 16 + fq * 4;
#pragma unroll
            for (int r = 0; r < 4; ++r) {
                const _Float16 h = (_Float16)acc[i][j][r] + bv;
                Out[(size_t)(mbase + r) * NDIM + n] = (float)h;
            }
        }
    }
}

extern "C" void kernel_launch(void* const* d_in, const int* in_sizes, int n_in,
                              void* d_out, int out_size, void* d_ws, size_t ws_size,
                              hipStream_t stream) {
    const float* x  = nullptr;
    const int*   q  = nullptr;
    const float* sc = nullptr;
    const float* zp = nullptr;
    const float* bi = nullptr;
    for (int i = 0; i < n_in; ++i) {
        switch (in_sizes[i]) {
            case 33554432: x = (const float*)d_in[i]; break;
            case 45088768: q = (const int*)d_in[i]; break;
            case 352256:   if (!sc) sc = (const float*)d_in[i];
                           else     zp = (const float*)d_in[i];
                           break;
            case 11008:    bi = (const float*)d_in[i]; break;
            default: break;
        }
    }
    if (!x || !q || !sc || !zp || !bi) {
        x  = (const float*)d_in[0];
        q  = (const int*)d_in[1];
        sc = (const float*)d_in[2];
        zp = (const float*)d_in[3];
        bi = (const float*)d_in[4];
    }
    float* out = (float*)d_out;

    if (ws_size >= WS_PACKED) {
        unsigned int* pq = (unsigned int*)d_ws;
        _Float16*     xh = (_Float16*)((char*)d_ws + PQ_BYTES);
        pack_q<<<5636096 / 256, 256, 0, stream>>>(q, pq);
        cvt_x<<<33554432 / 8 / 256, 256, 0, stream>>>(x, xh);
        wq_gemm_pl<<<(TOKENS / BM) * (NDIM / BN), 512, 0, stream>>>(xh, pq, sc, zp, bi, out);
    } else {
        dim3 grid(NDIM / 128, TOKENS / 128);
        wq_gemm_direct<<<grid, dim3(256), 0, stream>>>(x, q, sc, zp, bi, out);
    }
}

// Round 13
// 916.630 us; speedup vs baseline: 1.4576x; 1.0134x over previous
//
// Round 13: 8-phase schedule (m201 template) on the R10 data plan. 256x256x64, 8 waves,
// dbuf LDS 128KB (1 block/CU), per-phase {ds_read || stage-issue || s_barrier || 16-MFMA
// || s_barrier}, loads in flight across phases, ONE vmcnt drain per K-tile (at tile-end
// __syncthreads). pk-magic dequant B (q register-resident 1 tile ahead), gload_lds+XOR A.
#include <hip/hip_runtime.h>
#include <stdint.h>

#define TOKENS 8192
#define KDIM   4096
#define NDIM   11008
#define BM 256
#define BN 256
#define BK 64
#define KTILES (KDIM / BK)          // 64
#define QWPR 512                    // packed dwords per q row
#define PQ_BYTES (45088768u/8u*4u)  // 22544384
#define XH_BYTES (33554432ull*2ull) // 67108864
#define WS_PACKED ((size_t)PQ_BYTES + XH_BYTES)

typedef _Float16 f16x8 __attribute__((ext_vector_type(8)));
typedef _Float16 f16x2 __attribute__((ext_vector_type(2)));
typedef float    f32x4 __attribute__((ext_vector_type(4)));

typedef const __attribute__((address_space(1))) unsigned int* gptr_t;
typedef __attribute__((address_space(3))) unsigned int* lptr_t;

// ---- pass 1a: pack 8 nibbles -> 1 dword, PERMUTED [k0,k2,k4,k6,k1,k3,k5,k7]:
// ((d>>4p)&0x000F000F)|0x64006400 = fp16 pair (1024+k_{2p}, 1024+k_{2p+1}).
__global__ __launch_bounds__(256) void pack_q(const int* __restrict__ q,
                                              unsigned int* __restrict__ pq) {
    const unsigned int idx = blockIdx.x * 256 + threadIdx.x;
    const int4* p = (const int4*)(q + (size_t)idx * 8);
    const int4 a = p[0], b = p[1];
    unsigned int w = (unsigned int)(a.x & 15)
                   | ((unsigned int)(a.z & 15) << 4)
                   | ((unsigned int)(b.x & 15) << 8)
                   | ((unsigned int)(b.z & 15) << 12)
                   | ((unsigned int)(a.y & 15) << 16)
                   | ((unsigned int)(a.w & 15) << 20)
                   | ((unsigned int)(b.y & 15) << 24)
                   | ((unsigned int)(b.w & 15) << 28);
    pq[idx] = w;
}

// ---- pass 1b: x fp32 -> fp16 (exact) ----
__global__ __launch_bounds__(256) void cvt_x(const float* __restrict__ x,
                                             _Float16* __restrict__ xh) {
    const size_t idx = (size_t)(blockIdx.x * 256 + threadIdx.x) * 8;
    const float4* p = (const float4*)(x + idx);
    const float4 a = p[0], b = p[1];
    f16x8 o;
    o[0] = (_Float16)a.x; o[1] = (_Float16)a.y; o[2] = (_Float16)a.z; o[3] = (_Float16)a.w;
    o[4] = (_Float16)b.x; o[5] = (_Float16)b.y; o[6] = (_Float16)b.z; o[7] = (_Float16)b.w;
    *(f16x8*)(xh + idx) = o;
}

// ---- pass 2: 256^2 8-wave fused-dequant GEMM, 8-phase schedule ----
__global__ __launch_bounds__(512, 2)
void wq_gemm_8p(const _Float16* __restrict__ Xh, const unsigned int* __restrict__ Pq,
                const float* __restrict__ Sc, const float* __restrict__ Zp,
                const float* __restrict__ Bi, float* __restrict__ Out)
{
    __shared__ __align__(16) _Float16 As[2][BM * BK];   // 2 x 32 KB
    __shared__ __align__(16) _Float16 Bs[2][BN * BK];   // 2 x 32 KB

    const int t    = threadIdx.x;
    const int lane = t & 63;
    const int wid  = t >> 6;        // 0..7
    const int wmr  = wid >> 2;      // 0..1 : rows wmr*128..+128
    const int wnc  = wid & 3;       // 0..3 : cols wnc*64..+64

    // XCD-bijective, n-fastest (1376 = 8*172)
    const unsigned int bid = blockIdx.x;
    const unsigned int wg  = (bid & 7u) * 172u + (bid >> 3);
    const int m0 = (int)(wg / 43u) * BM;
    const int n0 = (int)(wg % 43u) * BN;

    // A staging (proven conflict-free): gload_lds, linear LDS dest, pre-XOR'd source:
    // phys blk = logical ^ (row&7). Issue i covers rows i*64 + wid*8 + (lane>>3).
    const int alr = lane >> 3;
    const int alb = lane & 7;
    const _Float16* aSrc = Xh + (size_t)(m0 + wid * 8 + alr) * KDIM + ((alb ^ alr) << 3);

    // B staging: row br = t>>1 (0..255), half bh = t&1 (4 packed dwords = 32 nibbles)
    const int br = t >> 1;
    const int bh = t & 1;
    const unsigned int* qsrc = Pq + (size_t)(n0 + br) * QWPR + bh * 4;
    const float* scp = Sc + n0 + br;
    const float* zpp = Zp + n0 + br;
    const int brx = br & 7;

    // fragment read map
    const int fr = lane & 15;
    const int fq = lane >> 4;       // 0..3
    const int fx = fr & 7;

    f32x4 acc[8][4];
#pragma unroll
    for (int i = 0; i < 8; ++i)
#pragma unroll
        for (int j = 0; j < 4; ++j)
            acc[i][j] = f32x4{0.f, 0.f, 0.f, 0.f};

    const f16x2 k1024 = {(_Float16)1024.0f, (_Float16)1024.0f};

// stage one A half-tile (2 gload_lds): h=0 -> rows 0..127, h=1 -> rows 128..255
#define A_HALF(buf, ktv, h) do {                                                      \
    _Pragma("unroll")                                                                 \
    for (int i_ = (h) * 2; i_ < (h) * 2 + 2; ++i_)                                    \
        __builtin_amdgcn_global_load_lds(                                             \
            (gptr_t)(const void*)(aSrc + (size_t)i_ * 64 * KDIM + (ktv) * BK),        \
            (lptr_t)(void*)(&As[buf][i_ * 4096 + wid * 512]), 16, 0, 0);              \
} while (0)

#define DEQ_STORE(buf, qvv, sfv, zfv) do {                                            \
    const f16x2 s2_ = {(_Float16)(sfv), (_Float16)(sfv)};                             \
    const f16x2 z2_ = {(_Float16)(zfv), (_Float16)(zfv)};                             \
    _Pragma("unroll")                                                                 \
    for (int d_ = 0; d_ < 4; ++d_) {                                                  \
        const unsigned int dw_ = ((const unsigned int*)&(qvv))[d_];                   \
        unsigned int o_[4];                                                           \
        _Pragma("unroll")                                                             \
        for (int p_ = 0; p_ < 4; ++p_) {                                              \
            unsigned int u_ = ((dw_ >> (4 * p_)) & 0x000F000Fu) | 0x64006400u;        \
            f16x2 h_ = __builtin_bit_cast(f16x2, u_);                                 \
            f16x2 q_ = h_ - k1024;                                                    \
            f16x2 w_ = q_ * s2_ + z2_;                                                \
            o_[p_] = __builtin_bit_cast(unsigned int, w_);                            \
        }                                                                             \
        const int kb_ = (bh * 4 + d_) ^ brx;                                          \
        *(uint4*)&Bs[buf][br * 64 + kb_ * 8] = uint4{o_[0], o_[1], o_[2], o_[3]};     \
    }                                                                                 \
} while (0)

// a-frag reads for m-pair p, MFMA cluster for m-pair p
#define A_READS(p_, b_) do {                                                          \
    _Pragma("unroll")                                                                 \
    for (int ii_ = 0; ii_ < 2; ++ii_)                                                 \
        _Pragma("unroll")                                                             \
        for (int kh_ = 0; kh_ < 2; ++kh_)                                             \
            af[ii_][kh_] = *(const f16x8*)&As[b_][                                    \
                (wmr * 128 + ((p_) * 2 + ii_) * 16 + fr) * 64 +                       \
                (((kh_ << 2) | fq) ^ fx) * 8];                                        \
} while (0)

#define MFMA_CLUSTER(p_) do {                                                         \
    __builtin_amdgcn_s_setprio(1);                                                    \
    _Pragma("unroll")                                                                 \
    for (int ii_ = 0; ii_ < 2; ++ii_)                                                 \
        _Pragma("unroll")                                                             \
        for (int j_ = 0; j_ < 4; ++j_) {                                              \
            acc[(p_) * 2 + ii_][j_] = __builtin_amdgcn_mfma_f32_16x16x32_f16(         \
                af[ii_][0], bc[j_][0], acc[(p_) * 2 + ii_][j_], 0, 0, 0);             \
            acc[(p_) * 2 + ii_][j_] = __builtin_amdgcn_mfma_f32_16x16x32_f16(         \
                af[ii_][1], bc[j_][1], acc[(p_) * 2 + ii_][j_], 0, 0, 0);             \
        }                                                                             \
    __builtin_amdgcn_s_setprio(0);                                                    \
} while (0)

    // ---- prologue: tile 0 fully staged, q(1) in regs ----
    A_HALF(0, 0, 0);
    A_HALF(0, 0, 1);
    {
        const uint4 q0v = *(const uint4*)(qsrc);
        const float sf0 = scp[0];
        const float zf0 = zpp[0];
        DEQ_STORE(0, q0v, sf0, zf0);     // compiler inserts the q0v vmcnt wait
    }
    uint4 qnext = *(const uint4*)(qsrc + 8);   // tile 1, group 0
    float sfn = scp[0], zfn = zpp[0];
    __syncthreads();                            // drain: A-DMA(0) + Bs[0] visible

    // ---- main loop: 4 phases per K-tile ----
    int cur = 0;
    for (int kt = 0; kt < KTILES; ++kt) {
        const int stage_on = (kt + 1 < KTILES);
        f16x8 bc[4][2], af[2][2];

        // phase 0: bc(8)+a0(4) reads; stage A-half0(kt+1)
#pragma unroll
        for (int j = 0; j < 4; ++j)
#pragma unroll
            for (int kh = 0; kh < 2; ++kh)
                bc[j][kh] = *(const f16x8*)&Bs[cur][(wnc * 64 + j * 16 + fr) * 64 +
                                                    (((kh << 2) | fq) ^ fx) * 8];
        A_READS(0, cur);
        if (stage_on) A_HALF(cur ^ 1, kt + 1, 0);
        __builtin_amdgcn_s_barrier();
        MFMA_CLUSTER(0);
        __builtin_amdgcn_s_barrier();

        // phase 1: a1 reads; stage A-half1(kt+1)
        A_READS(1, cur);
        if (stage_on) A_HALF(cur ^ 1, kt + 1, 1);
        __builtin_amdgcn_s_barrier();
        MFMA_CLUSTER(1);
        __builtin_amdgcn_s_barrier();

        // phase 2: a2 reads; issue q(kt+2) + s/z loads
        A_READS(2, cur);
        const int ktf = (kt + 2 < KTILES) ? kt + 2 : KTILES - 1;
        const uint4 qfut = *(const uint4*)(qsrc + (size_t)ktf * 8);
        const int gf = ktf >> 1;
        const float sff = scp[(size_t)gf * NDIM];
        const float zff = zpp[(size_t)gf * NDIM];
        __builtin_amdgcn_s_barrier();
        MFMA_CLUSTER(2);
        __builtin_amdgcn_s_barrier();

        // phase 3: a3 reads FIRST (MFMA operands ahead of writes in LDS queue),
        // then dequant+write B(kt+1) into buf^1 (nobody reads buf^1 this tile)
        A_READS(3, cur);
        if (stage_on) DEQ_STORE(cur ^ 1, qnext, sfn, zfn);
        __builtin_amdgcn_s_barrier();
        MFMA_CLUSTER(3);

        __syncthreads();   // ONE drain/tile: A-DMA(kt+1) landed, B writes visible;
                           // DMAs had >=3 phases in flight -> drain ~free
        qnext = qfut; sfn = sff; zfn = zff;
        cur ^= 1;
    }
#undef A_HALF
#undef DEQ_STORE
#undef A_READS
#undef MFMA_CLUSTER

    // epilogue: C/D map col=lane&15, row=(lane>>4)*4+reg; out = f32(f16(acc)+f16(bias))
#pragma unroll
    for (int j = 0; j < 4; ++j) {
        const int n = n0 + wnc * 64 + j * 16 + fr;
        const _Float16 bv = (_Float16)Bi[n];
#pragma unroll
        for (int im = 0; im < 8; ++im) {
            const int mbase = m0 + wmr * 128 + im * 16 + fq * 4;
#pragma unroll
            for (int r = 0; r < 4; ++r) {
                const _Float16 h = (_Float16)acc[im][j][r] + bv;
                __builtin_nontemporal_store((float)h, &Out[(size_t)(mbase + r) * NDIM + n]);
            }
        }
    }
}

// ---------------- fallback: round-5 direct kernel (no workspace) ----------------
__global__ __launch_bounds__(256, 2)
void wq_gemm_direct(const float* __restrict__ X,  const int* __restrict__ Qw,
                    const float* __restrict__ Sc, const float* __restrict__ Zp,
                    const float* __restrict__ Bi, float* __restrict__ Out)
{
    __shared__ __align__(16) _Float16 As[128 * 32];
    __shared__ __align__(16) _Float16 Bs[128 * 32];
    const int t = threadIdx.x, lane = t & 63, wid = t >> 6;
    const int wr = wid >> 1, wc = wid & 1;
    const int n0 = blockIdx.x * 128, m0 = blockIdx.y * 128;
    const int srow = t >> 1, shalf = (t & 1) << 4;
    const float* xsrc = X + (size_t)(m0 + srow) * KDIM + shalf;
    const int*   qsrc = Qw + (size_t)(n0 + srow) * KDIM + shalf;
    const float* scp = Sc + n0 + srow;
    const float* zpp = Zp + n0 + srow;
    _Float16* adst = As + srow * 32 + shalf;
    _Float16* bdst = Bs + srow * 32 + shalf;
    const int fr = lane & 15, fq = lane >> 4;
    const _Float16* ard = As + (wr * 64 + fr) * 32 + fq * 8;
    const _Float16* brd = Bs + (wc * 64 + fr) * 32 + fq * 8;
    f32x4 acc[4][4];
#pragma unroll
    for (int i = 0; i < 4; ++i)
#pragma unroll
        for (int j = 0; j < 4; ++j) acc[i][j] = f32x4{0.f, 0.f, 0.f, 0.f};
    for (int kt = 0; kt < KDIM / 32; ++kt) {
        const int k0 = kt * 32;
        const float4* xp = (const float4*)(xsrc + k0);
        const float4 x0 = xp[0], x1 = xp[1], x2 = xp[2], x3 = xp[3];
        const float xv[16] = {x0.x, x0.y, x0.z, x0.w, x1.x, x1.y, x1.z, x1.w,
                              x2.x, x2.y, x2.z, x2.w, x3.x, x3.y, x3.z, x3.w};
        f16x8 a0, a1;
#pragma unroll
        for (int j = 0; j < 8; ++j) { a0[j] = (_Float16)xv[j]; a1[j] = (_Float16)xv[j + 8]; }
        const int g = k0 >> 7;
        const float sf = scp[(size_t)g * NDIM];
        const float zf = zpp[(size_t)g * NDIM];
        const int4* qp = (const int4*)(qsrc + k0);
        const int4 q0 = qp[0], q1 = qp[1], q2 = qp[2], q3 = qp[3];
        const int qv[16] = {q0.x, q0.y, q0.z, q0.w, q1.x, q1.y, q1.z, q1.w,
                            q2.x, q2.y, q2.z, q2.w, q3.x, q3.y, q3.z, q3.w};
        f16x8 w0, w1;
#pragma unroll
        for (int j = 0; j < 8; ++j) {
            w0[j] = (_Float16)((float)qv[j]     * sf + zf);
            w1[j] = (_Float16)((float)qv[j + 8] * sf + zf);
        }
        *(f16x8*)adst = a0; *(f16x8*)(adst + 8) = a1;
        *(f16x8*)bdst = w0; *(f16x8*)(bdst + 8) = w1;
        __syncthreads();
        f16x8 a[4], b[4];
#pragma unroll
        for (int i = 0; i < 4; ++i) a[i] = *(const f16x8*)(ard + i * 16 * 32);
#pragma unroll
        for (int j = 0; j < 4; ++j) b[j] = *(const f16x8*)(brd + j * 16 * 32);
#pragma unroll
        for (int i = 0; i < 4; ++i)
#pragma unroll
            for (int j = 0; j < 4; ++j)
                acc[i][j] = __builtin_amdgcn_mfma_f32_16x16x32_f16(a[i], b[j], acc[i][j], 0, 0, 0);
        __syncthreads();
    }
#pragma unroll
    for (int j = 0; j < 4; ++j) {
        const int n = n0 + wc * 64 + j * 16 + fr;
        const _Float16 bv = (_Float16)Bi[n];
#pragma unroll
        for (int i = 0; i < 4; ++i) {
            const int mbase = m0 + wr * 64 + i * 16 + fq * 4;
#pragma unroll
            for (int r = 0; r < 4; ++r) {
                const _Float16 h = (_Float16)acc[i][j][r] + bv;
                Out[(size_t)(mbase + r) * NDIM + n] = (float)h;
            }
        }
    }
}

extern "C" void kernel_launch(void* const* d_in, const int* in_sizes, int n_in,
                              void* d_out, int out_size, void* d_ws, size_t ws_size,
                              hipStream_t stream) {
    const float* x  = nullptr;
    const int*   q  = nullptr;
    const float* sc = nullptr;
    const float* zp = nullptr;
    const float* bi = nullptr;
    for (int i = 0; i < n_in; ++i) {
        switch (in_sizes[i]) {
            case 33554432: x = (const float*)d_in[i]; break;
            case 45088768: q = (const int*)d_in[i]; break;
            case 352256:   if (!sc) sc = (const float*)d_in[i];
                           else     zp = (const float*)d_in[i];
                           break;
            case 11008:    bi = (const float*)d_in[i]; break;
            default: break;
        }
    }
    if (!x || !q || !sc || !zp || !bi) {
        x  = (const float*)d_in[0];
        q  = (const int*)d_in[1];
        sc = (const float*)d_in[2];
        zp = (const float*)d_in[3];
        bi = (const float*)d_in[4];
    }
    float* out = (float*)d_out;

    if (ws_size >= WS_PACKED) {
        unsigned int* pq = (unsigned int*)d_ws;
        _Float16*     xh = (_Float16*)((char*)d_ws + PQ_BYTES);
        pack_q<<<5636096 / 256, 256, 0, stream>>>(q, pq);
        cvt_x<<<33554432 / 8 / 256, 256, 0, stream>>>(x, xh);
        wq_gemm_8p<<<(TOKENS / BM) * (NDIM / BN), 512, 0, stream>>>(xh, pq, sc, zp, bi, out);
    } else {
        dim3 grid(NDIM / 128, TOKENS / 128);
        wq_gemm_direct<<<grid, dim3(256), 0, stream>>>(x, q, sc, zp, bi, out);
    }
}

// Round 14
// 805.678 us; speedup vs baseline: 1.6583x; 1.1377x over previous
//
// Round 14: B bypasses LDS entirely — transposed packed-q (pass-1 writes dword(n,o) at
// [(n>>4)*512+o]*16+(n&15)) makes per-lane q loads coalesced (256B/wave); pk-magic
// in-register dequant feeds MFMA directly. LDS holds only A (dbuf 64KB, gload_lds+XOR,
// proven). 256x256x64, 8 waves, 1 barrier/tile, q pipelined 1 tile ahead.
#include <hip/hip_runtime.h>
#include <stdint.h>

#define TOKENS 8192
#define KDIM   4096
#define NDIM   11008
#define BM 256
#define BN 256
#define BK 64
#define KTILES (KDIM / BK)          // 64
#define PQ_BYTES (45088768u/8u*4u)  // 22544384
#define XH_BYTES (33554432ull*2ull) // 67108864
#define WS_PACKED ((size_t)PQ_BYTES + XH_BYTES)

typedef _Float16 f16x8 __attribute__((ext_vector_type(8)));
typedef _Float16 f16x2 __attribute__((ext_vector_type(2)));
typedef float    f32x4 __attribute__((ext_vector_type(4)));

typedef const __attribute__((address_space(1))) unsigned int* gptr_t;
typedef __attribute__((address_space(3))) unsigned int* lptr_t;

// ---- pass 1a: TRANSPOSED permuted pack. Output dword for (column n, k-octet o) at
// index (n>>4)*8192 + o*16 + (n&15). Nibble order [k0,k2,k4,k6,k1,k3,k5,k7] so
// ((d>>4p)&0x000F000F)|0x64006400 = fp16 pair (1024+k_{2p}, 1024+k_{2p+1}).
__global__ __launch_bounds__(256) void pack_qt(const int* __restrict__ q,
                                               unsigned int* __restrict__ pqt) {
    const unsigned int g = blockIdx.x * 256 + threadIdx.x;   // 0..5636095
    const int c  = g & 15;
    const int o  = (g >> 4) & 511;
    const int np = g >> 13;
    const int n  = np * 16 + c;
    const int4* p = (const int4*)(q + (size_t)n * KDIM + o * 8);
    const int4 a = p[0], b = p[1];
    unsigned int w = (unsigned int)(a.x & 15)
                   | ((unsigned int)(a.z & 15) << 4)
                   | ((unsigned int)(b.x & 15) << 8)
                   | ((unsigned int)(b.z & 15) << 12)
                   | ((unsigned int)(a.y & 15) << 16)
                   | ((unsigned int)(a.w & 15) << 20)
                   | ((unsigned int)(b.y & 15) << 24)
                   | ((unsigned int)(b.w & 15) << 28);
    pqt[g] = w;
}

// ---- pass 1b: x fp32 -> fp16 (exact) ----
__global__ __launch_bounds__(256) void cvt_x(const float* __restrict__ x,
                                             _Float16* __restrict__ xh) {
    const size_t idx = (size_t)(blockIdx.x * 256 + threadIdx.x) * 8;
    const float4* p = (const float4*)(x + idx);
    const float4 a = p[0], b = p[1];
    f16x8 o;
    o[0] = (_Float16)a.x; o[1] = (_Float16)a.y; o[2] = (_Float16)a.z; o[3] = (_Float16)a.w;
    o[4] = (_Float16)b.x; o[5] = (_Float16)b.y; o[6] = (_Float16)b.z; o[7] = (_Float16)b.w;
    *(f16x8*)(xh + idx) = o;
}

// ---- pass 2: 256^2 8-wave GEMM, A in dbuf LDS, B dequanted in registers ----
__global__ __launch_bounds__(512, 2)
void wq_gemm_rq(const _Float16* __restrict__ Xh, const unsigned int* __restrict__ Pqt,
                const float* __restrict__ Sc, const float* __restrict__ Zp,
                const float* __restrict__ Bi, float* __restrict__ Out)
{
    __shared__ __align__(16) _Float16 As[2][BM * BK];   // 2 x 32 KB

    const int t    = threadIdx.x;
    const int lane = t & 63;
    const int wid  = t >> 6;        // 0..7
    const int wmr  = wid >> 2;      // 0..1 : rows wmr*128..+128
    const int wnc  = wid & 3;       // 0..3 : cols wnc*64..+64

    // XCD-bijective, n-fastest (1376 = 8*172)
    const unsigned int bid = blockIdx.x;
    const unsigned int wg  = (bid & 7u) * 172u + (bid >> 3);
    const int m0 = (int)(wg / 43u) * BM;
    const int n0 = (int)(wg % 43u) * BN;

    // A staging (proven conflict-free): gload_lds, linear LDS dest, pre-XOR'd source:
    // phys blk = logical ^ (row&7). Issue i covers rows i*64 + wid*8 + (lane>>3).
    const int alr = lane >> 3;
    const int alb = lane & 7;
    const _Float16* aSrc = Xh + (size_t)(m0 + wid * 8 + alr) * KDIM + ((alb ^ alr) << 3);

    // fragment read map
    const int fr = lane & 15;
    const int fq = lane >> 4;       // 0..3
    const int fx = fr & 7;

    // B per-lane sources (COALESCED: wave covers 64 consecutive dwords per (j,kh)):
    // dword addr = (n0+wnc*64)*512 + j*8192 + kt*128 + kh*64 + fq*16 + fr
    const unsigned int* qbase = Pqt + (size_t)(n0 + wnc * 64) * 512 + fq * 16 + fr;
    const float* scol = Sc + n0 + wnc * 64 + fr;   // + g*NDIM + j*16
    const float* zcol = Zp + n0 + wnc * 64 + fr;

    f32x4 acc[8][4];
#pragma unroll
    for (int i = 0; i < 8; ++i)
#pragma unroll
        for (int j = 0; j < 4; ++j)
            acc[i][j] = f32x4{0.f, 0.f, 0.f, 0.f};

    const f16x2 k1024 = {(_Float16)1024.0f, (_Float16)1024.0f};

#define A_STAGE(buf, ktv) do {                                                        \
    _Pragma("unroll")                                                                 \
    for (int i_ = 0; i_ < 4; ++i_)                                                    \
        __builtin_amdgcn_global_load_lds(                                             \
            (gptr_t)(const void*)(aSrc + (size_t)i_ * 64 * KDIM + (ktv) * BK),        \
            (lptr_t)(void*)(&As[buf][i_ * 4096 + wid * 512]), 16, 0, 0);              \
} while (0)

#define DEQ_REG(dst, dw, s2v, z2v) do {                                               \
    unsigned int o_[4];                                                               \
    _Pragma("unroll")                                                                 \
    for (int p_ = 0; p_ < 4; ++p_) {                                                  \
        unsigned int u_ = (((dw) >> (4 * p_)) & 0x000F000Fu) | 0x64006400u;           \
        f16x2 h_ = __builtin_bit_cast(f16x2, u_);                                     \
        f16x2 q_ = h_ - k1024;                                                        \
        f16x2 w_ = q_ * (s2v) + (z2v);                                                \
        o_[p_] = __builtin_bit_cast(unsigned int, w_);                                \
    }                                                                                 \
    (dst) = __builtin_bit_cast(f16x8, uint4{o_[0], o_[1], o_[2], o_[3]});             \
} while (0)

    unsigned int qc[8], qf[8];
    f16x2 s2c[4], z2c[4], s2n[4], z2n[4];

    // ---- prologue: A tile 0 DMA; q(0) + s/z(group 0) ----
    A_STAGE(0, 0);
#pragma unroll
    for (int j = 0; j < 4; ++j)
#pragma unroll
        for (int kh = 0; kh < 2; ++kh)
            qc[j * 2 + kh] = qbase[j * 8192 + kh * 64];
#pragma unroll
    for (int j = 0; j < 4; ++j) {
        const float s_ = scol[j * 16];
        const float z_ = zcol[j * 16];
        s2c[j] = f16x2{(_Float16)s_, (_Float16)s_};
        z2c[j] = f16x2{(_Float16)z_, (_Float16)z_};
        s2n[j] = s2c[j]; z2n[j] = z2c[j];
    }
#pragma unroll
    for (int i = 0; i < 8; ++i) qf[i] = qc[i];
    __syncthreads();                      // A(0) landed

    int cur = 0;
    for (int kt = 0; kt < KTILES; ++kt) {
        const bool more = (kt + 1 < KTILES);

        // issue all next-tile loads up front (drained by this tile's end barrier)
        if (more) {
            A_STAGE(cur ^ 1, kt + 1);
#pragma unroll
            for (int j = 0; j < 4; ++j)
#pragma unroll
                for (int kh = 0; kh < 2; ++kh)
                    qf[j * 2 + kh] = qbase[j * 8192 + (kt + 1) * 128 + kh * 64];
            const int gn = (kt + 1) >> 1;
#pragma unroll
            for (int j = 0; j < 4; ++j) {
                const float s_ = scol[(size_t)gn * NDIM + j * 16];
                const float z_ = zcol[(size_t)gn * NDIM + j * 16];
                s2n[j] = f16x2{(_Float16)s_, (_Float16)s_};
                z2n[j] = f16x2{(_Float16)z_, (_Float16)z_};
            }
        }

        // dequant current B in registers (no LDS round-trip)
        f16x8 bf[4][2];
#pragma unroll
        for (int j = 0; j < 4; ++j) {
            DEQ_REG(bf[j][0], qc[j * 2 + 0], s2c[j], z2c[j]);
            DEQ_REG(bf[j][1], qc[j * 2 + 1], s2c[j], z2c[j]);
        }

        // MFMA: 4 m-pair clusters; a-frags read per cluster (compiler prefetches ahead)
#pragma unroll
        for (int p = 0; p < 4; ++p) {
            f16x8 af[2][2];
#pragma unroll
            for (int ii = 0; ii < 2; ++ii)
#pragma unroll
                for (int kh = 0; kh < 2; ++kh)
                    af[ii][kh] = *(const f16x8*)&As[cur][(wmr * 128 + (p * 2 + ii) * 16 + fr) * 64 +
                                                         (((kh << 2) | fq) ^ fx) * 8];
            __builtin_amdgcn_s_setprio(1);
#pragma unroll
            for (int ii = 0; ii < 2; ++ii)
#pragma unroll
                for (int j = 0; j < 4; ++j) {
                    acc[p * 2 + ii][j] = __builtin_amdgcn_mfma_f32_16x16x32_f16(
                        af[ii][0], bf[j][0], acc[p * 2 + ii][j], 0, 0, 0);
                    acc[p * 2 + ii][j] = __builtin_amdgcn_mfma_f32_16x16x32_f16(
                        af[ii][1], bf[j][1], acc[p * 2 + ii][j], 0, 0, 0);
                }
            __builtin_amdgcn_s_setprio(0);
        }

        __syncthreads();   // drains A-DMA(kt+1) + q/sz loads; reads of cur done
#pragma unroll
        for (int i = 0; i < 8; ++i) qc[i] = qf[i];
#pragma unroll
        for (int j = 0; j < 4; ++j) { s2c[j] = s2n[j]; z2c[j] = z2n[j]; }
        cur ^= 1;
    }
#undef A_STAGE
#undef DEQ_REG

    // epilogue: C/D map col=lane&15, row=(lane>>4)*4+reg; out = f32(f16(acc)+f16(bias))
#pragma unroll
    for (int j = 0; j < 4; ++j) {
        const int n = n0 + wnc * 64 + j * 16 + fr;
        const _Float16 bv = (_Float16)Bi[n];
#pragma unroll
        for (int im = 0; im < 8; ++im) {
            const int mbase = m0 + wmr * 128 + im * 16 + fq * 4;
#pragma unroll
            for (int r = 0; r < 4; ++r) {
                const _Float16 h = (_Float16)acc[im][j][r] + bv;
                __builtin_nontemporal_store((float)h, &Out[(size_t)(mbase + r) * NDIM + n]);
            }
        }
    }
}

// ---------------- fallback: round-5 direct kernel (no workspace) ----------------
__global__ __launch_bounds__(256, 2)
void wq_gemm_direct(const float* __restrict__ X,  const int* __restrict__ Qw,
                    const float* __restrict__ Sc, const float* __restrict__ Zp,
                    const float* __restrict__ Bi, float* __restrict__ Out)
{
    __shared__ __align__(16) _Float16 As[128 * 32];
    __shared__ __align__(16) _Float16 Bs[128 * 32];
    const int t = threadIdx.x, lane = t & 63, wid = t >> 6;
    const int wr = wid >> 1, wc = wid & 1;
    const int n0 = blockIdx.x * 128, m0 = blockIdx.y * 128;
    const int srow = t >> 1, shalf = (t & 1) << 4;
    const float* xsrc = X + (size_t)(m0 + srow) * KDIM + shalf;
    const int*   qsrc = Qw + (size_t)(n0 + srow) * KDIM + shalf;
    const float* scp = Sc + n0 + srow;
    const float* zpp = Zp + n0 + srow;
    _Float16* adst = As + srow * 32 + shalf;
    _Float16* bdst = Bs + srow * 32 + shalf;
    const int fr = lane & 15, fq = lane >> 4;
    const _Float16* ard = As + (wr * 64 + fr) * 32 + fq * 8;
    const _Float16* brd = Bs + (wc * 64 + fr) * 32 + fq * 8;
    f32x4 acc[4][4];
#pragma unroll
    for (int i = 0; i < 4; ++i)
#pragma unroll
        for (int j = 0; j < 4; ++j) acc[i][j] = f32x4{0.f, 0.f, 0.f, 0.f};
    for (int kt = 0; kt < KDIM / 32; ++kt) {
        const int k0 = kt * 32;
        const float4* xp = (const float4*)(xsrc + k0);
        const float4 x0 = xp[0], x1 = xp[1], x2 = xp[2], x3 = xp[3];
        const float xv[16] = {x0.x, x0.y, x0.z, x0.w, x1.x, x1.y, x1.z, x1.w,
                              x2.x, x2.y, x2.z, x2.w, x3.x, x3.y, x3.z, x3.w};
        f16x8 a0, a1;
#pragma unroll
        for (int j = 0; j < 8; ++j) { a0[j] = (_Float16)xv[j]; a1[j] = (_Float16)xv[j + 8]; }
        const int g = k0 >> 7;
        const float sf = scp[(size_t)g * NDIM];
        const float zf = zpp[(size_t)g * NDIM];
        const int4* qp = (const int4*)(qsrc + k0);
        const int4 q0 = qp[0], q1 = qp[1], q2 = qp[2], q3 = qp[3];
        const int qv[16] = {q0.x, q0.y, q0.z, q0.w, q1.x, q1.y, q1.z, q1.w,
                            q2.x, q2.y, q2.z, q2.w, q3.x, q3.y, q3.z, q3.w};
        f16x8 w0, w1;
#pragma unroll
        for (int j = 0; j < 8; ++j) {
            w0[j] = (_Float16)((float)qv[j]     * sf + zf);
            w1[j] = (_Float16)((float)qv[j + 8] * sf + zf);
        }
        *(f16x8*)adst = a0; *(f16x8*)(adst + 8) = a1;
        *(f16x8*)bdst = w0; *(f16x8*)(bdst + 8) = w1;
        __syncthreads();
        f16x8 a[4], b[4];
#pragma unroll
        for (int i = 0; i < 4; ++i) a[i] = *(const f16x8*)(ard + i * 16 * 32);
#pragma unroll
        for (int j = 0; j < 4; ++j) b[j] = *(const f16x8*)(brd + j * 16 * 32);
#pragma unroll
        for (int i = 0; i < 4; ++i)
#pragma unroll
            for (int j = 0; j < 4; ++j)
                acc[i][j] = __builtin_amdgcn_mfma_f32_16x16x32_f16(a[i], b[j], acc[i][j], 0, 0, 0);
        __syncthreads();
    }
#pragma unroll
    for (int j = 0; j < 4; ++j) {
        const int n = n0 + wc * 64 + j * 16 + fr;
        const _Float16 bv = (_Float16)Bi[n];
#pragma unroll
        for (int i = 0; i < 4; ++i) {
            const int mbase = m0 + wr * 64 + i * 16 + fq * 4;
#pragma unroll
            for (int r = 0; r < 4; ++r) {
                const _Float16 h = (_Float16)acc[i][j][r] + bv;
                Out[(size_t)(mbase + r) * NDIM + n] = (float)h;
            }
        }
    }
}

extern "C" void kernel_launch(void* const* d_in, const int* in_sizes, int n_in,
                              void* d_out, int out_size, void* d_ws, size_t ws_size,
                              hipStream_t stream) {
    const float* x  = nullptr;
    const int*   q  = nullptr;
    const float* sc = nullptr;
    const float* zp = nullptr;
    const float* bi = nullptr;
    for (int i = 0; i < n_in; ++i) {
        switch (in_sizes[i]) {
            case 33554432: x = (const float*)d_in[i]; break;
            case 45088768: q = (const int*)d_in[i]; break;
            case 352256:   if (!sc) sc = (const float*)d_in[i];
                           else     zp = (const float*)d_in[i];
                           break;
            case 11008:    bi = (const float*)d_in[i]; break;
            default: break;
        }
    }
    if (!x || !q || !sc || !zp || !bi) {
        x  = (const float*)d_in[0];
        q  = (const int*)d_in[1];
        sc = (const float*)d_in[2];
        zp = (const float*)d_in[3];
        bi = (const float*)d_in[4];
    }
    float* out = (float*)d_out;

    if (ws_size >= WS_PACKED) {
        unsigned int* pqt = (unsigned int*)d_ws;
        _Float16*     xh  = (_Float16*)((char*)d_ws + PQ_BYTES);
        pack_qt<<<5636096 / 256, 256, 0, stream>>>(q, pqt);
        cvt_x<<<33554432 / 8 / 256, 256, 0, stream>>>(x, xh);
        wq_gemm_rq<<<(TOKENS / BM) * (NDIM / BN), 512, 0, stream>>>(xh, pqt, sc, zp, bi, out);
    } else {
        dim3 grid(NDIM / 128, TOKENS / 128);
        wq_gemm_direct<<<grid, dim3(256), 0, stream>>>(x, q, sc, zp, bi, out);
    }
}

// Round 15
// 745.245 us; speedup vs baseline: 1.7928x; 1.0811x over previous
//
// Round 15: R14 data plan (reg-B via transposed packed q, A-only LDS) with HALVED block:
// 128x256 tile, 256 threads / 4 waves, LDS 32KB -> 2 blocks/CU so barrier drains of one
// block are covered by the other block's MFMA. Per-wave work identical to R14.
#include <hip/hip_runtime.h>
#include <stdint.h>

#define TOKENS 8192
#define KDIM   4096
#define NDIM   11008
#define BM 128
#define BN 256
#define BK 64
#define KTILES (KDIM / BK)          // 64
#define PQ_BYTES (45088768u/8u*4u)  // 22544384
#define XH_BYTES (33554432ull*2ull) // 67108864
#define WS_PACKED ((size_t)PQ_BYTES + XH_BYTES)

typedef _Float16 f16x8 __attribute__((ext_vector_type(8)));
typedef _Float16 f16x2 __attribute__((ext_vector_type(2)));
typedef float    f32x4 __attribute__((ext_vector_type(4)));

typedef const __attribute__((address_space(1))) unsigned int* gptr_t;
typedef __attribute__((address_space(3))) unsigned int* lptr_t;

// ---- pass 1a: TRANSPOSED permuted pack. dword(column n, k-octet o) stored at
// (n>>4)*8192 + o*16 + (n&15). Nibble order [k0,k2,k4,k6,k1,k3,k5,k7] so
// ((d>>4p)&0x000F000F)|0x64006400 = fp16 pair (1024+k_{2p}, 1024+k_{2p+1}).
__global__ __launch_bounds__(256) void pack_qt(const int* __restrict__ q,
                                               unsigned int* __restrict__ pqt) {
    const unsigned int g = blockIdx.x * 256 + threadIdx.x;   // 0..5636095
    const int c  = g & 15;
    const int o  = (g >> 4) & 511;
    const int np = g >> 13;
    const int n  = np * 16 + c;
    const int4* p = (const int4*)(q + (size_t)n * KDIM + o * 8);
    const int4 a = p[0], b = p[1];
    unsigned int w = (unsigned int)(a.x & 15)
                   | ((unsigned int)(a.z & 15) << 4)
                   | ((unsigned int)(b.x & 15) << 8)
                   | ((unsigned int)(b.z & 15) << 12)
                   | ((unsigned int)(a.y & 15) << 16)
                   | ((unsigned int)(a.w & 15) << 20)
                   | ((unsigned int)(b.y & 15) << 24)
                   | ((unsigned int)(b.w & 15) << 28);
    pqt[g] = w;
}

// ---- pass 1b: x fp32 -> fp16 (exact) ----
__global__ __launch_bounds__(256) void cvt_x(const float* __restrict__ x,
                                             _Float16* __restrict__ xh) {
    const size_t idx = (size_t)(blockIdx.x * 256 + threadIdx.x) * 8;
    const float4* p = (const float4*)(x + idx);
    const float4 a = p[0], b = p[1];
    f16x8 o;
    o[0] = (_Float16)a.x; o[1] = (_Float16)a.y; o[2] = (_Float16)a.z; o[3] = (_Float16)a.w;
    o[4] = (_Float16)b.x; o[5] = (_Float16)b.y; o[6] = (_Float16)b.z; o[7] = (_Float16)b.w;
    *(f16x8*)(xh + idx) = o;
}

// ---- pass 2: 128x256 4-wave GEMM, A in dbuf LDS (32KB), B dequanted in registers ----
__global__ __launch_bounds__(256, 2)
void wq_gemm_h2(const _Float16* __restrict__ Xh, const unsigned int* __restrict__ Pqt,
                const float* __restrict__ Sc, const float* __restrict__ Zp,
                const float* __restrict__ Bi, float* __restrict__ Out)
{
    __shared__ __align__(16) _Float16 As[2][BM * BK];   // 2 x 16 KB

    const int t    = threadIdx.x;
    const int lane = t & 63;
    const int wid  = t >> 6;        // 0..3
    const int wnc  = wid;           // wave owns cols wnc*64..+64; all share 128 m-rows

    // XCD-bijective, n-fastest (2752 = 8*344; 344 = 8 m-rows of 43)
    const unsigned int bid = blockIdx.x;
    const unsigned int wg  = (bid & 7u) * 344u + (bid >> 3);
    const int m0 = (int)(wg / 43u) * BM;
    const int n0 = (int)(wg % 43u) * BN;

    // A staging (proven conflict-free): gload_lds, linear LDS dest, pre-XOR'd source:
    // phys blk = logical ^ (row&7). Issue i covers rows i*32 + wid*8 + (lane>>3).
    const int alr = lane >> 3;
    const int alb = lane & 7;
    const _Float16* aSrc = Xh + (size_t)(m0 + wid * 8 + alr) * KDIM + ((alb ^ alr) << 3);

    // fragment read map
    const int fr = lane & 15;
    const int fq = lane >> 4;       // 0..3
    const int fx = fr & 7;

    // B per-lane sources (coalesced: wave covers 64 consecutive dwords per (j,kh)):
    // dword addr = (n0+wnc*64)*512 + j*8192 + kt*128 + kh*64 + fq*16 + fr
    const unsigned int* qbase = Pqt + (size_t)(n0 + wnc * 64) * 512 + fq * 16 + fr;
    const float* scol = Sc + n0 + wnc * 64 + fr;   // + g*NDIM + j*16
    const float* zcol = Zp + n0 + wnc * 64 + fr;

    f32x4 acc[8][4];
#pragma unroll
    for (int i = 0; i < 8; ++i)
#pragma unroll
        for (int j = 0; j < 4; ++j)
            acc[i][j] = f32x4{0.f, 0.f, 0.f, 0.f};

    const f16x2 k1024 = {(_Float16)1024.0f, (_Float16)1024.0f};

#define A_STAGE(buf, ktv) do {                                                        \
    _Pragma("unroll")                                                                 \
    for (int i_ = 0; i_ < 4; ++i_)                                                    \
        __builtin_amdgcn_global_load_lds(                                             \
            (gptr_t)(const void*)(aSrc + (size_t)i_ * 32 * KDIM + (ktv) * BK),        \
            (lptr_t)(void*)(&As[buf][i_ * 2048 + wid * 512]), 16, 0, 0);              \
} while (0)

#define DEQ_REG(dst, dw, s2v, z2v) do {                                               \
    unsigned int o_[4];                                                               \
    _Pragma("unroll")                                                                 \
    for (int p_ = 0; p_ < 4; ++p_) {                                                  \
        unsigned int u_ = (((dw) >> (4 * p_)) & 0x000F000Fu) | 0x64006400u;           \
        f16x2 h_ = __builtin_bit_cast(f16x2, u_);                                     \
        f16x2 q_ = h_ - k1024;                                                        \
        f16x2 w_ = q_ * (s2v) + (z2v);                                                \
        o_[p_] = __builtin_bit_cast(unsigned int, w_);                                \
    }                                                                                 \
    (dst) = __builtin_bit_cast(f16x8, uint4{o_[0], o_[1], o_[2], o_[3]});             \
} while (0)

    unsigned int qc[8], qf[8];
    f16x2 s2c[4], z2c[4], s2n[4], z2n[4];

    // ---- prologue: A tile 0 DMA; q(0) + s/z(group 0) ----
    A_STAGE(0, 0);
#pragma unroll
    for (int j = 0; j < 4; ++j)
#pragma unroll
        for (int kh = 0; kh < 2; ++kh)
            qc[j * 2 + kh] = qbase[j * 8192 + kh * 64];
#pragma unroll
    for (int j = 0; j < 4; ++j) {
        const float s_ = scol[j * 16];
        const float z_ = zcol[j * 16];
        s2c[j] = f16x2{(_Float16)s_, (_Float16)s_};
        z2c[j] = f16x2{(_Float16)z_, (_Float16)z_};
        s2n[j] = s2c[j]; z2n[j] = z2c[j];
    }
#pragma unroll
    for (int i = 0; i < 8; ++i) qf[i] = qc[i];
    __syncthreads();                      // A(0) landed

    int cur = 0;
    for (int kt = 0; kt < KTILES; ++kt) {
        const bool more = (kt + 1 < KTILES);

        // issue all next-tile loads up front (drained by this tile's end barrier)
        if (more) {
            A_STAGE(cur ^ 1, kt + 1);
#pragma unroll
            for (int j = 0; j < 4; ++j)
#pragma unroll
                for (int kh = 0; kh < 2; ++kh)
                    qf[j * 2 + kh] = qbase[j * 8192 + (kt + 1) * 128 + kh * 64];
            const int gn = (kt + 1) >> 1;
#pragma unroll
            for (int j = 0; j < 4; ++j) {
                const float s_ = scol[(size_t)gn * NDIM + j * 16];
                const float z_ = zcol[(size_t)gn * NDIM + j * 16];
                s2n[j] = f16x2{(_Float16)s_, (_Float16)s_};
                z2n[j] = f16x2{(_Float16)z_, (_Float16)z_};
            }
        }

        // dequant current B in registers (no LDS round-trip)
        f16x8 bf[4][2];
#pragma unroll
        for (int j = 0; j < 4; ++j) {
            DEQ_REG(bf[j][0], qc[j * 2 + 0], s2c[j], z2c[j]);
            DEQ_REG(bf[j][1], qc[j * 2 + 1], s2c[j], z2c[j]);
        }

        // MFMA: 4 m-pair clusters over the shared 128 rows
#pragma unroll
        for (int p = 0; p < 4; ++p) {
            f16x8 af[2][2];
#pragma unroll
            for (int ii = 0; ii < 2; ++ii)
#pragma unroll
                for (int kh = 0; kh < 2; ++kh)
                    af[ii][kh] = *(const f16x8*)&As[cur][((p * 2 + ii) * 16 + fr) * 64 +
                                                         (((kh << 2) | fq) ^ fx) * 8];
            __builtin_amdgcn_s_setprio(1);
#pragma unroll
            for (int ii = 0; ii < 2; ++ii)
#pragma unroll
                for (int j = 0; j < 4; ++j) {
                    acc[p * 2 + ii][j] = __builtin_amdgcn_mfma_f32_16x16x32_f16(
                        af[ii][0], bf[j][0], acc[p * 2 + ii][j], 0, 0, 0);
                    acc[p * 2 + ii][j] = __builtin_amdgcn_mfma_f32_16x16x32_f16(
                        af[ii][1], bf[j][1], acc[p * 2 + ii][j], 0, 0, 0);
                }
            __builtin_amdgcn_s_setprio(0);
        }

        __syncthreads();   // drains A-DMA(kt+1) + q/sz loads; reads of cur done
#pragma unroll
        for (int i = 0; i < 8; ++i) qc[i] = qf[i];
#pragma unroll
        for (int j = 0; j < 4; ++j) { s2c[j] = s2n[j]; z2c[j] = z2n[j]; }
        cur ^= 1;
    }
#undef A_STAGE
#undef DEQ_REG

    // epilogue: C/D map col=lane&15, row=(lane>>4)*4+reg; out = f32(f16(acc)+f16(bias))
#pragma unroll
    for (int j = 0; j < 4; ++j) {
        const int n = n0 + wnc * 64 + j * 16 + fr;
        const _Float16 bv = (_Float16)Bi[n];
#pragma unroll
        for (int im = 0; im < 8; ++im) {
            const int mbase = m0 + im * 16 + fq * 4;
#pragma unroll
            for (int r = 0; r < 4; ++r) {
                const _Float16 h = (_Float16)acc[im][j][r] + bv;
                __builtin_nontemporal_store((float)h, &Out[(size_t)(mbase + r) * NDIM + n]);
            }
        }
    }
}

// ---------------- fallback: round-5 direct kernel (no workspace) ----------------
__global__ __launch_bounds__(256, 2)
void wq_gemm_direct(const float* __restrict__ X,  const int* __restrict__ Qw,
                    const float* __restrict__ Sc, const float* __restrict__ Zp,
                    const float* __restrict__ Bi, float* __restrict__ Out)
{
    __shared__ __align__(16) _Float16 As[128 * 32];
    __shared__ __align__(16) _Float16 Bs[128 * 32];
    const int t = threadIdx.x, lane = t & 63, wid = t >> 6;
    const int wr = wid >> 1, wc = wid & 1;
    const int n0 = blockIdx.x * 128, m0 = blockIdx.y * 128;
    const int srow = t >> 1, shalf = (t & 1) << 4;
    const float* xsrc = X + (size_t)(m0 + srow) * KDIM + shalf;
    const int*   qsrc = Qw + (size_t)(n0 + srow) * KDIM + shalf;
    const float* scp = Sc + n0 + srow;
    const float* zpp = Zp + n0 + srow;
    _Float16* adst = As + srow * 32 + shalf;
    _Float16* bdst = Bs + srow * 32 + shalf;
    const int fr = lane & 15, fq = lane >> 4;
    const _Float16* ard = As + (wr * 64 + fr) * 32 + fq * 8;
    const _Float16* brd = Bs + (wc * 64 + fr) * 32 + fq * 8;
    f32x4 acc[4][4];
#pragma unroll
    for (int i = 0; i < 4; ++i)
#pragma unroll
        for (int j = 0; j < 4; ++j) acc[i][j] = f32x4{0.f, 0.f, 0.f, 0.f};
    for (int kt = 0; kt < KDIM / 32; ++kt) {
        const int k0 = kt * 32;
        const float4* xp = (const float4*)(xsrc + k0);
        const float4 x0 = xp[0], x1 = xp[1], x2 = xp[2], x3 = xp[3];
        const float xv[16] = {x0.x, x0.y, x0.z, x0.w, x1.x, x1.y, x1.z, x1.w,
                              x2.x, x2.y, x2.z, x2.w, x3.x, x3.y, x3.z, x3.w};
        f16x8 a0, a1;
#pragma unroll
        for (int j = 0; j < 8; ++j) { a0[j] = (_Float16)xv[j]; a1[j] = (_Float16)xv[j + 8]; }
        const int g = k0 >> 7;
        const float sf = scp[(size_t)g * NDIM];
        const float zf = zpp[(size_t)g * NDIM];
        const int4* qp = (const int4*)(qsrc + k0);
        const int4 q0 = qp[0], q1 = qp[1], q2 = qp[2], q3 = qp[3];
        const int qv[16] = {q0.x, q0.y, q0.z, q0.w, q1.x, q1.y, q1.z, q1.w,
                            q2.x, q2.y, q2.z, q2.w, q3.x, q3.y, q3.z, q3.w};
        f16x8 w0, w1;
#pragma unroll
        for (int j = 0; j < 8; ++j) {
            w0[j] = (_Float16)((float)qv[j]     * sf + zf);
            w1[j] = (_Float16)((float)qv[j + 8] * sf + zf);
        }
        *(f16x8*)adst = a0; *(f16x8*)(adst + 8) = a1;
        *(f16x8*)bdst = w0; *(f16x8*)(bdst + 8) = w1;
        __syncthreads();
        f16x8 a[4], b[4];
#pragma unroll
        for (int i = 0; i < 4; ++i) a[i] = *(const f16x8*)(ard + i * 16 * 32);
#pragma unroll
        for (int j = 0; j < 4; ++j) b[j] = *(const f16x8*)(brd + j * 16 * 32);
#pragma unroll
        for (int i = 0; i < 4; ++i)
#pragma unroll
            for (int j = 0; j < 4; ++j)
                acc[i][j] = __builtin_amdgcn_mfma_f32_16x16x32_f16(a[i], b[j], acc[i][j], 0, 0, 0);
        __syncthreads();
    }
#pragma unroll
    for (int j = 0; j < 4; ++j) {
        const int n = n0 + wc * 64 + j * 16 + fr;
        const _Float16 bv = (_Float16)Bi[n];
#pragma unroll
        for (int i = 0; i < 4; ++i) {
            const int mbase = m0 + wr * 64 + i * 16 + fq * 4;
#pragma unroll
            for (int r = 0; r < 4; ++r) {
                const _Float16 h = (_Float16)acc[i][j][r] + bv;
                Out[(size_t)(mbase + r) * NDIM + n] = (float)h;
            }
        }
    }
}

extern "C" void kernel_launch(void* const* d_in, const int* in_sizes, int n_in,
                              void* d_out, int out_size, void* d_ws, size_t ws_size,
                              hipStream_t stream) {
    const float* x  = nullptr;
    const int*   q  = nullptr;
    const float* sc = nullptr;
    const float* zp = nullptr;
    const float* bi = nullptr;
    for (int i = 0; i < n_in; ++i) {
        switch (in_sizes[i]) {
            case 33554432: x = (const float*)d_in[i]; break;
            case 45088768: q = (const int*)d_in[i]; break;
            case 352256:   if (!sc) sc = (const float*)d_in[i];
                           else     zp = (const float*)d_in[i];
                           break;
            case 11008:    bi = (const float*)d_in[i]; break;
            default: break;
        }
    }
    if (!x || !q || !sc || !zp || !bi) {
        x  = (const float*)d_in[0];
        q  = (const int*)d_in[1];
        sc = (const float*)d_in[2];
        zp = (const float*)d_in[3];
        bi = (const float*)d_in[4];
    }
    float* out = (float*)d_out;

    if (ws_size >= WS_PACKED) {
        unsigned int* pqt = (unsigned int*)d_ws;
        _Float16*     xh  = (_Float16*)((char*)d_ws + PQ_BYTES);
        pack_qt<<<5636096 / 256, 256, 0, stream>>>(q, pqt);
        cvt_x<<<33554432 / 8 / 256, 256, 0, stream>>>(x, xh);
        wq_gemm_h2<<<(TOKENS / BM) * (NDIM / BN), 256, 0, stream>>>(xh, pqt, sc, zp, bi, out);
    } else {
        dim3 grid(NDIM / 128, TOKENS / 128);
        wq_gemm_direct<<<grid, dim3(256), 0, stream>>>(x, q, sc, zp, bi, out);
    }
}